// Round 10
// baseline (1198.484 us; speedup 1.0000x reference)
//
#include <hip/hip_runtime.h>
#include <stdint.h>

typedef __bf16 bf8_t __attribute__((ext_vector_type(8)));
typedef float f32x4 __attribute__((ext_vector_type(4)));

#define EPSV 1e-5f

__device__ __forceinline__ float b2f(unsigned short u) {
  union { uint32_t i; float f; } v; v.i = ((uint32_t)u) << 16; return v.f;
}
__device__ __forceinline__ unsigned short f2b(float f) {
  union { float f; uint32_t i; } v; v.f = f;
  uint32_t x = v.i;
  return (unsigned short)((x + 0x7fffu + ((x >> 16) & 1u)) >> 16);  // RNE
}

// async global->LDS DMA, 16 B per lane (lds dest = wave-uniform base + lane*16)
typedef __attribute__((address_space(1))) void gvoid;
typedef __attribute__((address_space(3))) void lvoid;
__device__ __forceinline__ void gload16(const unsigned short* g, unsigned short* l) {
  __builtin_amdgcn_global_load_lds((gvoid*)g, (lvoid*)l, 16, 0, 0);
}

// ---------------------------------------------------------------- fp32 -> bf16 convert
__global__ __launch_bounds__(256) void cvt_f2b(const float* __restrict__ in,
                                               unsigned short* __restrict__ out, int n) {
  int gid = blockIdx.x * 256 + threadIdx.x;
  if (gid < n) out[gid] = f2b(in[gid]);
}

// ---------------------------------------------------------------- stage 1: y1 = xyz @ W1^T (K=3), fp32
__global__ __launch_bounds__(256) void stage1(const float* __restrict__ xyz,
                                              const float* __restrict__ W1,
                                              float* __restrict__ y1) {
  int gid = blockIdx.x * 256 + threadIdx.x;   // 8192*64
  int r = gid >> 6, o = gid & 63;
  float x0 = xyz[r*3+0], x1 = xyz[r*3+1], x2 = xyz[r*3+2];
  float w0 = W1[o*3+0], w1 = W1[o*3+1], w2 = W1[o*3+2];
  y1[gid] = x0*w0 + x1*w1 + x2*w2;
}

// ---------------------------------------------------------------- per-channel sum/sumsq (fp32, stage-1 only)
__global__ __launch_bounds__(256) void colstats(const float* __restrict__ y, int O,
                                                float* __restrict__ acc) {
  int col = blockIdx.x * 64 + (threadIdx.x & 63);
  long rbase = (long)blockIdx.y * 1024 + (threadIdx.x >> 6);
  float s = 0.f, s2 = 0.f;
  for (int i = 0; i < 256; ++i) {
    float v = y[(rbase + (long)i*4) * O + col];
    s += v; s2 += v*v;
  }
  __shared__ float red[512];
  red[threadIdx.x] = s; red[256 + threadIdx.x] = s2;
  __syncthreads();
  if (threadIdx.x < 64) {
    float S = 0.f, S2 = 0.f;
    for (int j = 0; j < 4; ++j) { S += red[threadIdx.x + 64*j]; S2 += red[256 + threadIdx.x + 64*j]; }
    atomicAdd(&acc[col], S);
    atomicAdd(&acc[O + col], S2);
  }
}

// ---------------------------------------------------------------- BN finalize
__global__ void finalize_stats(const float* __restrict__ acc, const float* __restrict__ g,
                               const float* __restrict__ b, int O, float invCount,
                               float* __restrict__ a, float* __restrict__ cc) {
  int c = blockIdx.x * 256 + threadIdx.x;
  if (c >= O) return;
  float m = acc[c] * invCount;
  float v = fmaxf(acc[O + c] * invCount - m*m, 0.f);
  float rs = rsqrtf(v + EPSV);
  float A = g[c] * rs;
  a[c] = A; cc[c] = b[c] - m * A;
}

// ---------------------------------------------------------------- BN+ReLU fp32 -> bf16 (single rounding), 8/thread
__global__ __launch_bounds__(256) void bnrelu_cast(const float* __restrict__ y,
                                                   const float* __restrict__ a,
                                                   const float* __restrict__ cc,
                                                   int Omask,
                                                   unsigned short* __restrict__ out) {
  long base = ((long)blockIdx.x * 256 + threadIdx.x) * 8;
  int c = (int)(base & (long)Omask);
  float4 f0 = *(const float4*)(y + base);
  float4 f1 = *(const float4*)(y + base + 4);
  float4 a0 = *(const float4*)(a + c);
  float4 a1 = *(const float4*)(a + c + 4);
  float4 c0 = *(const float4*)(cc + c);
  float4 c1 = *(const float4*)(cc + c + 4);
  uint4 v;
  unsigned short* u = (unsigned short*)&v;
  u[0] = f2b(fmaxf(a0.x*f0.x + c0.x, 0.f));
  u[1] = f2b(fmaxf(a0.y*f0.y + c0.y, 0.f));
  u[2] = f2b(fmaxf(a0.z*f0.z + c0.z, 0.f));
  u[3] = f2b(fmaxf(a0.w*f0.w + c0.w, 0.f));
  u[4] = f2b(fmaxf(a1.x*f1.x + c1.x, 0.f));
  u[5] = f2b(fmaxf(a1.y*f1.y + c1.y, 0.f));
  u[6] = f2b(fmaxf(a1.z*f1.z + c1.z, 0.f));
  u[7] = f2b(fmaxf(a1.w*f1.w + c1.w, 0.f));
  *(uint4*)(out + base) = v;
}

// ---------------------------------------------------------------- gathered column stats:
// v[r,c] = Z[fs[r], c] + C[r>>3, c];  acc[c] += sum, acc[O+c] += sumsq  (fp32)
__global__ __launch_bounds__(256) void gstats(const float* __restrict__ Z,
                                              const float* __restrict__ C,
                                              const int* __restrict__ fs,
                                              int O,              // 512 or 1024
                                              float* __restrict__ acc) {
  const int t = threadIdx.x;
  const int cq = O >> 2;                 // float4 cols
  const int c = (t & (cq - 1)) << 2;
  const int rof = t / cq;
  const int rstep = 256 / cq;            // 2 (O=512) or 1 (O=1024)
  const long rbase = (long)blockIdx.x * 128;   // 128 rows per block
  float s0=0,s1=0,s2=0,s3=0, q0=0,q1=0,q2=0,q3=0;
  for (int r = rof; r < 128; r += rstep) {
    const long rr = rbase + r;
    const long zr = (long)fs[rr] * O;
    const long cr = (rr >> 3) * (long)O;
    float4 z = *(const float4*)(Z + zr + c);
    float4 y = *(const float4*)(C + cr + c);
    float v0=z.x+y.x, v1=z.y+y.y, v2=z.z+y.z, v3=z.w+y.w;
    s0+=v0; s1+=v1; s2+=v2; s3+=v3;
    q0+=v0*v0; q1+=v1*v1; q2+=v2*v2; q3+=v3*v3;
  }
  atomicAdd(&acc[c+0], s0); atomicAdd(&acc[c+1], s1);
  atomicAdd(&acc[c+2], s2); atomicAdd(&acc[c+3], s3);
  atomicAdd(&acc[O+c+0], q0); atomicAdd(&acc[O+c+1], q1);
  atomicAdd(&acc[O+c+2], q2); atomicAdd(&acc[O+c+3], q3);
}

// ---------------------------------------------------------------- gathered BN+ReLU+cast:
// out[r,c] = f2b(relu(a[c]*(Z[fs[r],c] + C[r>>3,c]) + cc[c]))   (single rounding)
__global__ __launch_bounds__(256) void gbn(const float* __restrict__ Z,
                                           const float* __restrict__ C,
                                           const int* __restrict__ fs,
                                           const float* __restrict__ a,
                                           const float* __restrict__ cc,
                                           int cprShift,            // log2(O/8): 6 for O=512, 7 for O=1024
                                           unsigned short* __restrict__ out) {
  const int O = 8 << cprShift;
  long gid = (long)blockIdx.x * 256 + threadIdx.x;
  long r = gid >> cprShift;
  int c = (int)(gid & ((1 << cprShift) - 1)) << 3;
  const long zr = (long)fs[r] * O;
  const long cr = (r >> 3) * (long)O;
  float4 z0 = *(const float4*)(Z + zr + c), z1 = *(const float4*)(Z + zr + c + 4);
  float4 y0 = *(const float4*)(C + cr + c), y1 = *(const float4*)(C + cr + c + 4);
  float4 a0 = *(const float4*)(a + c),      a1 = *(const float4*)(a + c + 4);
  float4 b0 = *(const float4*)(cc + c),     b1 = *(const float4*)(cc + c + 4);
  uint4 v; unsigned short* u = (unsigned short*)&v;
  u[0] = f2b(fmaxf(a0.x*(z0.x+y0.x) + b0.x, 0.f));
  u[1] = f2b(fmaxf(a0.y*(z0.y+y0.y) + b0.y, 0.f));
  u[2] = f2b(fmaxf(a0.z*(z0.z+y0.z) + b0.z, 0.f));
  u[3] = f2b(fmaxf(a0.w*(z0.w+y0.w) + b0.w, 0.f));
  u[4] = f2b(fmaxf(a1.x*(z1.x+y1.x) + b1.x, 0.f));
  u[5] = f2b(fmaxf(a1.y*(z1.y+y1.y) + b1.y, 0.f));
  u[6] = f2b(fmaxf(a1.z*(z1.z+y1.z) + b1.z, 0.f));
  u[7] = f2b(fmaxf(a1.w*(z1.w+y1.w) + b1.w, 0.f));
  *(uint4*)(out + r*O + c) = v;
}

// ---------------------------------------------------------------- KNN top-8
__global__ __launch_bounds__(256) void knn_kernel(const float* __restrict__ xyz,
                                                  int* __restrict__ flat_src) {
  __shared__ float px[1024], py[1024], pz[1024], sq[1024];
  int b = blockIdx.x;
  for (int i = threadIdx.x; i < 1024; i += 256) {
    float x = xyz[(b*1024 + i)*3 + 0];
    float y = xyz[(b*1024 + i)*3 + 1];
    float z = xyz[(b*1024 + i)*3 + 2];
    px[i] = x; py[i] = y; pz[i] = z; sq[i] = x*x + y*y + z*z;
  }
  __syncthreads();
  int q = blockIdx.y * 256 + threadIdx.x;
  float qx = px[q], qy = py[q], qz = pz[q], qs = sq[q];
  float bd[8]; int bi[8];
  #pragma unroll
  for (int j = 0; j < 8; ++j) { bd[j] = 3.4e38f; bi[j] = 0; }
  for (int m = 0; m < 1024; ++m) {
    float dot = qx*px[m] + qy*py[m] + qz*pz[m];
    float d2 = qs + sq[m] - 2.f*dot;      // exact reference formula (tie behavior)
    if (d2 < bd[7]) {
      bd[7] = d2; bi[7] = m;
      #pragma unroll
      for (int j = 7; j > 0; --j) {
        if (bd[j] < bd[j-1]) {
          float td = bd[j]; bd[j] = bd[j-1]; bd[j-1] = td;
          int ti = bi[j]; bi[j] = bi[j-1]; bi[j-1] = ti;
        }
      }
    }
  }
  #pragma unroll
  for (int j = 0; j < 8; ++j) flat_src[(b*1024 + q)*8 + j] = b*1024 + bi[j];
}

// ---------------------------------------------------------------- weight diff: fp32 -> bf16
__global__ __launch_bounds__(256) void wdiff(const float* __restrict__ W, int H,
                                             unsigned short* __restrict__ WD) {
  int gid = blockIdx.x * 256 + threadIdx.x;
  int o = gid / H, h = gid - o*H;
  WD[gid] = f2b(W[o*2*H + H + h] - W[o*2*H + h]);
}

// ---------------------------------------------------------------- MFMA GEMM (128x256 tile, BK=64, XOR-swizzled LDS)
// Widened from 128x128 (r9): each block computes TWO col-tiles off one staged A-tile.
// Per wave-tile: 64 MFMA vs 32, barriers/FLOP halved, DMA/MFMA 0.25->0.19,
// ds_read/MFMA 0.5->0.375. K-loop sync mechanics, XOR swizzle, gload_lds staging and
// XCD-chunked remap identical to r9 (all HW-verified there). Per-element accumulation
// order unchanged -> bit-identical output.
// 4 waves: wave grid 2 rows x 2 cols; per-wave output 64 rows x 128 cols, acc[4][8].
// LDS 48 KB. Maxmin epilogue: register/shuffle (no LDS, no barriers).
union GemmSmem {
  struct { unsigned short A[128*64]; unsigned short W[256*64]; } st;   // 48 KB
  struct { float redS[256*8]; float redS2[256*8]; } fst;               // 16 KB (fused stats)
};

__global__ __launch_bounds__(256) void gemm_kernel(
    const unsigned short* __restrict__ A16,   // bf16 A
    long strideA,
    const int* __restrict__ rowmap,
    const unsigned short* __restrict__ W, int strideW,
    int K, int O,                             // K multiple of 64; col-tile = 256
    const float* __restrict__ addC,           // fp32 [rows/8][O] added pre-store/stats
    unsigned short* __restrict__ outB,        // plain path: bf16 out (stats still fp32)
    float* __restrict__ outF,                 // plain path: fp32 out
    float* __restrict__ statsP,               // plain path: fused col stats, or NULL
    float* __restrict__ ymax, float* __restrict__ ymin,  // maxmin path
    float* __restrict__ statsMM)
{
  __shared__ GemmSmem sm;

  const int t = threadIdx.x;
  const int wave = t >> 6, lane = t & 63, quad = lane >> 4, lr = lane & 15;
  const int wr0 = (wave >> 1) * 64;         // wave row origin (2 row-waves)
  const int wc0 = (wave & 1) * 128;         // wave col origin (2 col-waves x 128)

  // XCD-chunked block remap (grid = dim3(NCB, NRB), nwg % 8 == 0)
  const int nwgx = gridDim.x;
  const int nwg = nwgx * gridDim.y;
  const int id = blockIdx.y * nwgx + blockIdx.x;
  const int swz = (id & 7) * (nwg >> 3) + (id >> 3);
  const int rowB = swz / nwgx;
  const int colB = swz - rowB * nwgx;
  const long rowBase = (long)rowB * 128;
  const int colBase = colB * 256;

  // staging geometry: lane l -> row-in-8 (l>>3), phys chunk l&7;
  // source logical chunk = (l&7)^(l>>3)  (XOR involution, row&7 = l>>3)
  const int lrow = lane >> 3;                       // 0..7
  const int lchk = ((lane & 7) ^ lrow) << 3;        // source chunk offset in shorts
  // A: wave w stages rows [w*32, +32) -> 4 issues
  const unsigned short* pa[4];
  #pragma unroll
  for (int j = 0; j < 4; ++j) {
    int r = wave*32 + j*8 + lrow;
    long sA = rowmap ? (long)rowmap[rowBase + r] : rowBase + r;
    pa[j] = A16 + sA * strideA + lchk;
  }
  // W: wave w stages rows [w*64, +64) of the 256-row col panel -> 8 issues
  const unsigned short* pw[8];
  #pragma unroll
  for (int j = 0; j < 8; ++j) {
    int r = wave*64 + j*8 + lrow;
    pw[j] = W + (long)(colBase + r) * strideW + lchk;
  }

  f32x4 acc[4][8];
  #pragma unroll
  for (int i = 0; i < 4; ++i)
    #pragma unroll
    for (int j = 0; j < 8; ++j)
      acc[i][j] = (f32x4){0.f, 0.f, 0.f, 0.f};

  for (int k0 = 0; k0 < K; k0 += 64) {
    __syncthreads();                 // previous iter's LDS reads done
    #pragma unroll
    for (int j = 0; j < 4; ++j)
      gload16(pa[j] + k0, &sm.st.A[wave*2048 + j*512]);
    #pragma unroll
    for (int j = 0; j < 8; ++j)
      gload16(pw[j] + k0, &sm.st.W[wave*4096 + j*512]);
    __syncthreads();                 // drains vmcnt(0): DMA data visible

    #pragma unroll
    for (int kk = 0; kk < 2; ++kk) {
      const int coff = (((kk*4 + quad) ^ (lr & 7)) << 3);   // swizzled chunk, constant/lane
      bf8_t af[4];
      #pragma unroll
      for (int s = 0; s < 4; ++s)
        af[s] = *(const bf8_t*)&sm.st.A[(wr0 + s*16 + lr)*64 + coff];
      #pragma unroll
      for (int sc = 0; sc < 8; ++sc) {
        bf8_t bfr = *(const bf8_t*)&sm.st.W[(wc0 + sc*16 + lr)*64 + coff];
        #pragma unroll
        for (int sr = 0; sr < 4; ++sr)
          acc[sr][sc] = __builtin_amdgcn_mfma_f32_16x16x32_bf16(af[sr], bfr, acc[sr][sc], 0, 0, 0);
      }
    }
  }

  if (!ymax) {
    // plain epilogue: center-add, bf16/fp32 store, optional fused per-channel stats (fp32 pre-round)
    float s[8] = {0,0,0,0,0,0,0,0}, s2[8] = {0,0,0,0,0,0,0,0};
    #pragma unroll
    for (int sc = 0; sc < 8; ++sc) {
      int col = colBase + wc0 + sc*16 + lr;
      #pragma unroll
      for (int sr = 0; sr < 4; ++sr) {
        #pragma unroll
        for (int r = 0; r < 4; ++r) {
          long row = rowBase + wr0 + sr*16 + quad*4 + r;
          float v = acc[sr][sc][r];
          if (addC) v += addC[(row >> 3) * (long)O + col];
          if (outF) outF[row * (long)O + col] = v;
          else      outB[row * (long)O + col] = f2b(v);
          s[sc] += v; s2[sc] += v*v;
        }
      }
    }
    if (statsP) {
      __syncthreads();   // all waves done reading sm.st before aliasing as fst
      int q8 = quad + 4*(wave >> 1);
      #pragma unroll
      for (int sc = 0; sc < 8; ++sc) {
        int colL = wc0 + sc*16 + lr;
        sm.fst.redS[colL*8 + q8]  = s[sc];
        sm.fst.redS2[colL*8 + q8] = s2[sc];
      }
      __syncthreads();
      {
        float S = 0.f, S2 = 0.f;
        #pragma unroll
        for (int j = 0; j < 8; ++j) { S += sm.fst.redS[t*8 + j]; S2 += sm.fst.redS2[t*8 + j]; }
        atomicAdd(&statsP[colBase + t], S);
        atomicAdd(&statsP[O + colBase + t], S2);
      }
    }
  } else {
    // maxmin epilogue: register/shuffle, no LDS, no barriers.
    #pragma unroll
    for (int sc = 0; sc < 8; ++sc) {
      int col = colBase + wc0 + sc*16 + lr;
      float s = 0.f, s2v = 0.f;
      #pragma unroll
      for (int sr = 0; sr < 4; ++sr) {
        float mx = acc[sr][sc][0], mn = acc[sr][sc][0];
        s += acc[sr][sc][0]; s2v += acc[sr][sc][0]*acc[sr][sc][0];
        #pragma unroll
        for (int r = 1; r < 4; ++r) {
          float v = acc[sr][sc][r];
          mx = fmaxf(mx, v); mn = fminf(mn, v);
          s += v; s2v += v*v;
        }
        mx = fmaxf(mx, __shfl_xor(mx, 16));
        mn = fminf(mn, __shfl_xor(mn, 16));
        if ((quad & 1) == 0) {
          long orow = (long)rowB*16 + (wave >> 1)*8 + sr*2 + (quad >> 1);
          ymax[orow * O + col] = mx;
          ymin[orow * O + col] = mn;
        }
      }
      s   += __shfl_xor(s, 16);   s   += __shfl_xor(s, 32);
      s2v += __shfl_xor(s2v, 16); s2v += __shfl_xor(s2v, 32);
      if (quad == 0) {
        atomicAdd(&statsMM[col], s);
        atomicAdd(&statsMM[O + col], s2v);
      }
    }
  }
}

// ---------------------------------------------------------------- l0 from A2 maxmin
__global__ __launch_bounds__(256) void to_l0(const float* __restrict__ ymax,
                                             const float* __restrict__ ymin,
                                             const float* __restrict__ a, const float* __restrict__ cc,
                                             unsigned short* __restrict__ l0) {
  int gid = blockIdx.x * 256 + threadIdx.x;   // 8192*512
  int c = gid & 511;
  float A = a[c];
  float v = (A >= 0.f) ? ymax[gid] : ymin[gid];
  l0[gid] = f2b(fmaxf(A*v + cc[c], 0.f));
}

// ---------------------------------------------------------------- final BN+ReLU + transpose, fp32
__global__ __launch_bounds__(256) void final_out(const float* __restrict__ ymax,
                                                 const float* __restrict__ ymin,
                                                 const float* __restrict__ a, const float* __restrict__ cc,
                                                 float* __restrict__ out) {
  __shared__ float tile[32][33];
  int b = blockIdx.x, ct = blockIdx.y * 32, nt = blockIdx.z * 32;
  int tc = threadIdx.x & 31, tr = threadIdx.x >> 5;
  #pragma unroll
  for (int i = 0; i < 4; ++i) {
    int n = nt + tr + i*8;
    int c = ct + tc;
    float A = a[c];
    long idx = ((long)(b*1024 + n))*1024 + c;
    float v = (A >= 0.f) ? ymax[idx] : ymin[idx];
    tile[tr + i*8][tc] = fmaxf(A*v + cc[c], 0.f);
  }
  __syncthreads();
  #pragma unroll
  for (int i = 0; i < 4; ++i) {
    int c = ct + tr + i*8;
    int n = nt + tc;
    out[((long)(b*1024 + c))*1024 + n] = tile[tc][tr + i*8];
  }
}

// ================================================================ host
extern "C" void kernel_launch(void* const* d_in, const int* in_sizes, int n_in,
                              void* d_out, int out_size, void* d_ws, size_t ws_size,
                              hipStream_t stream) {
  const float* xyz = (const float*)d_in[0];
  const float* W1  = (const float*)d_in[1];
  const float* g1  = (const float*)d_in[2];
  const float* b1  = (const float*)d_in[3];
  const float* W2  = (const float*)d_in[4];
  const float* g2  = (const float*)d_in[5];
  const float* b2  = (const float*)d_in[6];
  const float* WA1 = (const float*)d_in[7];
  const float* gA1 = (const float*)d_in[8];
  const float* bA1 = (const float*)d_in[9];
  const float* WA2 = (const float*)d_in[10];
  const float* gA2 = (const float*)d_in[11];
  const float* bA2 = (const float*)d_in[12];
  const float* WB1 = (const float*)d_in[13];
  const float* gB1 = (const float*)d_in[14];
  const float* bB1 = (const float*)d_in[15];
  const float* WB2 = (const float*)d_in[16];
  const float* gB2 = (const float*)d_in[17];
  const float* bB2 = (const float*)d_in[18];
  float* out = (float*)d_out;

  char* w = (char*)d_ws;
  const size_t MB = 1048576;

  // -------- small zone [0, 8 MB) --------
  size_t off = 0;
  auto nxt = [&](size_t bytes) { void* p = w + off; off = (off + bytes + 255) & ~(size_t)255; return p; };
  int*            flat_src = (int*)nxt(262144);
  unsigned short* W2b  = (unsigned short*)nxt(32768);
  unsigned short* WA1b = (unsigned short*)nxt(524288);
  unsigned short* WDA  = (unsigned short*)nxt(262144);
  unsigned short* WA2b = (unsigned short*)nxt(524288);
  unsigned short* WB1b = (unsigned short*)nxt(2097152);
  unsigned short* WDB  = (unsigned short*)nxt(1048576);
  unsigned short* WB2b = (unsigned short*)nxt(2097152);
  float* statsZone = (float*)nxt(27136);
  float* affZone   = (float*)nxt(27136);

  // -------- big zone (lifetime-aliased, peak 208 MB) --------
  float*          yCA   = (float*)(w + 177*MB);           // [177,193)  A1 center out (16 MB)
  float*          y1f   = (float*)(w + 193*MB);           // [193,195)
  unsigned short* x2in  = (unsigned short*)(w + 195*MB);  // [195,196)
  float*          y2f   = (float*)(w + 196*MB);           // [196,204)
  unsigned short* xA1   = (unsigned short*)(w + 204*MB);  // [204,208)
  float*          zA    = (float*)(w + 8*MB);             // [8,24)    xA1 @ WA1lo^T (16 MB)
  unsigned short* xA2   = (unsigned short*)(w + 24*MB);   // [24,88)   gathered+BN'd (64 MB)
  float*          ymaxA = (float*)(w + 88*MB);            // [88,104)
  float*          yminA = (float*)(w + 104*MB);           // [104,120)
  unsigned short* l0    = (unsigned short*)(w + 200*MB);  // [200,208) xA1 dead
  float*          yCB   = (float*)(w + 8*MB);             // [8,40)    zA/xA2 dead (32 MB)
  float*          zB    = (float*)(w + 40*MB);            // [40,72)   l0 @ WB1lo^T (32 MB)
  unsigned short* yB1b  = (unsigned short*)(w + 72*MB);   // [72,200)  gathered+BN'd (128 MB)
  float*          ymaxB = (float*)(w + 8*MB);             // [8,40)    yCB dead
  float*          yminB = (float*)(w + 40*MB);            // [40,72)   zB dead

  float* acc1  = statsZone;          // 2*64
  float* acc2  = statsZone + 128;    // 2*256
  float* accA1 = statsZone + 640;    // 2*512
  float* accA2 = statsZone + 1664;   // 2*512
  float* accB1 = statsZone + 2688;   // 2*1024
  float* accB2 = statsZone + 4736;   // 2*1024

  float* a1  = affZone;        float* cc1  = affZone + 64;
  float* a2  = affZone + 128;  float* cc2  = affZone + 384;
  float* aA1 = affZone + 640;  float* ccA1 = affZone + 1152;
  float* aA2 = affZone + 1664; float* ccA2 = affZone + 2176;
  float* aB1 = affZone + 2688; float* ccB1 = affZone + 3712;
  float* aB2 = affZone + 4736; float* ccB2 = affZone + 5760;

  hipMemsetAsync(statsZone, 0, 6784 * 4, stream);

  // weight conversions + diffs
  cvt_f2b<<<64, 256, 0, stream>>>(W2, W2b, 16384);
  cvt_f2b<<<1024, 256, 0, stream>>>(WA1, WA1b, 262144);
  cvt_f2b<<<1024, 256, 0, stream>>>(WA2, WA2b, 262144);
  cvt_f2b<<<4096, 256, 0, stream>>>(WB1, WB1b, 1048576);
  cvt_f2b<<<4096, 256, 0, stream>>>(WB2, WB2b, 1048576);
  wdiff<<<512, 256, 0, stream>>>(WA1, 256, WDA);
  wdiff<<<2048, 256, 0, stream>>>(WB1, 512, WDB);

  // stage 1 + BN
  stage1<<<2048, 256, 0, stream>>>(xyz, W1, y1f);
  colstats<<<dim3(1, 8), 256, 0, stream>>>(y1f, 64, acc1);
  finalize_stats<<<1, 256, 0, stream>>>(acc1, g1, b1, 64, 1.f/8192.f, a1, cc1);
  bnrelu_cast<<<256, 256, 0, stream>>>(y1f, a1, cc1, 63, x2in);

  // stage 2 (bf16 A, fp32 out, fused stats)   grid = (colTiles256, rowBlocks)
  gemm_kernel<<<dim3(1, 64), 256, 0, stream>>>(x2in, 64, nullptr,
                                               W2b, 64, 64, 256,
                                               nullptr, nullptr, y2f, acc2, nullptr, nullptr, nullptr);
  finalize_stats<<<1, 256, 0, stream>>>(acc2, g2, b2, 256, 1.f/8192.f, a2, cc2);
  bnrelu_cast<<<1024, 256, 0, stream>>>(y2f, a2, cc2, 255, xA1);

  // knn
  knn_kernel<<<dim3(8, 4), 256, 0, stream>>>(xyz, flat_src);

  // stage A1: center GEMM + main GEMM at M=8192 (gather moved out of the GEMM:
  // out[r] = zA[fs[r]] + yCA[r>>3]). WA1b is FULL (512x512): strideW=512, K=256.
  gemm_kernel<<<dim3(2, 64), 256, 0, stream>>>(xA1, 256, nullptr,
                                               WDA, 256, 256, 512,
                                               nullptr, nullptr, yCA, nullptr, nullptr, nullptr, nullptr);
  gemm_kernel<<<dim3(2, 64), 256, 0, stream>>>(xA1, 256, nullptr,
                                               WA1b, 512, 256, 512,
                                               nullptr, nullptr, zA, nullptr, nullptr, nullptr, nullptr);
  gstats<<<512, 256, 0, stream>>>(zA, yCA, flat_src, 512, accA1);
  finalize_stats<<<2, 256, 0, stream>>>(accA1, gA1, bA1, 512, 1.f/65536.f, aA1, ccA1);
  gbn<<<16384, 256, 0, stream>>>(zA, yCA, flat_src, aA1, ccA1, 6, xA2);

  // stage A2: maxmin GEMM, plain bf16 A
  gemm_kernel<<<dim3(2, 512), 256, 0, stream>>>(xA2, 512, nullptr,
                                                WA2b, 512, 512, 512,
                                                nullptr, nullptr, nullptr, nullptr, ymaxA, yminA, accA2);
  finalize_stats<<<2, 256, 0, stream>>>(accA2, gA2, bA2, 512, 1.f/65536.f, aA2, ccA2);
  to_l0<<<16384, 256, 0, stream>>>(ymaxA, yminA, aA2, ccA2, l0);

  // stage B1: center GEMM + main GEMM at M=8192, then gathered stats + BN.
  // WB1b is FULL (1024x1024): strideW=1024, K=512.
  gemm_kernel<<<dim3(4, 64), 256, 0, stream>>>(l0, 512, nullptr,
                                               WDB, 512, 512, 1024,
                                               nullptr, nullptr, yCB, nullptr, nullptr, nullptr, nullptr);
  gemm_kernel<<<dim3(4, 64), 256, 0, stream>>>(l0, 512, nullptr,
                                               WB1b, 1024, 512, 1024,
                                               nullptr, nullptr, zB, nullptr, nullptr, nullptr, nullptr);
  gstats<<<512, 256, 0, stream>>>(zB, yCB, flat_src, 1024, accB1);
  finalize_stats<<<4, 256, 0, stream>>>(accB1, gB1, bB1, 1024, 1.f/65536.f, aB1, ccB1);
  gbn<<<32768, 256, 0, stream>>>(zB, yCB, flat_src, aB1, ccB1, 7, yB1b);

  // stage B2: maxmin GEMM, plain bf16 A
  gemm_kernel<<<dim3(4, 512), 256, 0, stream>>>(yB1b, 1024, nullptr,
                                                WB2b, 1024, 1024, 1024,
                                                nullptr, nullptr, nullptr, nullptr, ymaxB, yminB, accB2);
  finalize_stats<<<4, 256, 0, stream>>>(accB2, gB2, bB2, 1024, 1.f/65536.f, aB2, ccB2);

  // final
  final_out<<<dim3(8, 32, 32), 256, 0, stream>>>(ymaxB, yminB, aB2, ccB2, out);
}

// Round 12
// 1103.244 us; speedup vs baseline: 1.0863x; 1.0863x over previous
//
#include <hip/hip_runtime.h>
#include <stdint.h>

typedef __bf16 bf8_t __attribute__((ext_vector_type(8)));
typedef float f32x4 __attribute__((ext_vector_type(4)));

#define EPSV 1e-5f

__device__ __forceinline__ float b2f(unsigned short u) {
  union { uint32_t i; float f; } v; v.i = ((uint32_t)u) << 16; return v.f;
}
__device__ __forceinline__ unsigned short f2b(float f) {
  union { float f; uint32_t i; } v; v.f = f;
  uint32_t x = v.i;
  return (unsigned short)((x + 0x7fffu + ((x >> 16) & 1u)) >> 16);  // RNE
}

// async global->LDS DMA, 16 B per lane (lds dest = wave-uniform base + lane*16)
typedef __attribute__((address_space(1))) void gvoid;
typedef __attribute__((address_space(3))) void lvoid;
__device__ __forceinline__ void gload16(const unsigned short* g, unsigned short* l) {
  __builtin_amdgcn_global_load_lds((gvoid*)g, (lvoid*)l, 16, 0, 0);
}

// ---------------------------------------------------------------- fp32 -> bf16 convert
__global__ __launch_bounds__(256) void cvt_f2b(const float* __restrict__ in,
                                               unsigned short* __restrict__ out, int n) {
  int gid = blockIdx.x * 256 + threadIdx.x;
  if (gid < n) out[gid] = f2b(in[gid]);
}

// ---------------------------------------------------------------- stage 1: y1 = xyz @ W1^T (K=3), fp32
__global__ __launch_bounds__(256) void stage1(const float* __restrict__ xyz,
                                              const float* __restrict__ W1,
                                              float* __restrict__ y1) {
  int gid = blockIdx.x * 256 + threadIdx.x;   // 8192*64
  int r = gid >> 6, o = gid & 63;
  float x0 = xyz[r*3+0], x1 = xyz[r*3+1], x2 = xyz[r*3+2];
  float w0 = W1[o*3+0], w1 = W1[o*3+1], w2 = W1[o*3+2];
  y1[gid] = x0*w0 + x1*w1 + x2*w2;
}

// ---------------------------------------------------------------- per-channel sum/sumsq (fp32, stage-1 only)
__global__ __launch_bounds__(256) void colstats(const float* __restrict__ y, int O,
                                                float* __restrict__ acc) {
  int col = blockIdx.x * 64 + (threadIdx.x & 63);
  long rbase = (long)blockIdx.y * 1024 + (threadIdx.x >> 6);
  float s = 0.f, s2 = 0.f;
  for (int i = 0; i < 256; ++i) {
    float v = y[(rbase + (long)i*4) * O + col];
    s += v; s2 += v*v;
  }
  __shared__ float red[512];
  red[threadIdx.x] = s; red[256 + threadIdx.x] = s2;
  __syncthreads();
  if (threadIdx.x < 64) {
    float S = 0.f, S2 = 0.f;
    for (int j = 0; j < 4; ++j) { S += red[threadIdx.x + 64*j]; S2 += red[256 + threadIdx.x + 64*j]; }
    atomicAdd(&acc[col], S);
    atomicAdd(&acc[O + col], S2);
  }
}

// ---------------------------------------------------------------- BN finalize
__global__ void finalize_stats(const float* __restrict__ acc, const float* __restrict__ g,
                               const float* __restrict__ b, int O, float invCount,
                               float* __restrict__ a, float* __restrict__ cc) {
  int c = blockIdx.x * 256 + threadIdx.x;
  if (c >= O) return;
  float m = acc[c] * invCount;
  float v = fmaxf(acc[O + c] * invCount - m*m, 0.f);
  float rs = rsqrtf(v + EPSV);
  float A = g[c] * rs;
  a[c] = A; cc[c] = b[c] - m * A;
}

// ---------------------------------------------------------------- BN+ReLU fp32 -> bf16 (single rounding), 8/thread
__global__ __launch_bounds__(256) void bnrelu_cast(const float* __restrict__ y,
                                                   const float* __restrict__ a,
                                                   const float* __restrict__ cc,
                                                   int Omask,
                                                   unsigned short* __restrict__ out) {
  long base = ((long)blockIdx.x * 256 + threadIdx.x) * 8;
  int c = (int)(base & (long)Omask);
  float4 f0 = *(const float4*)(y + base);
  float4 f1 = *(const float4*)(y + base + 4);
  float4 a0 = *(const float4*)(a + c);
  float4 a1 = *(const float4*)(a + c + 4);
  float4 c0 = *(const float4*)(cc + c);
  float4 c1 = *(const float4*)(cc + c + 4);
  uint4 v;
  unsigned short* u = (unsigned short*)&v;
  u[0] = f2b(fmaxf(a0.x*f0.x + c0.x, 0.f));
  u[1] = f2b(fmaxf(a0.y*f0.y + c0.y, 0.f));
  u[2] = f2b(fmaxf(a0.z*f0.z + c0.z, 0.f));
  u[3] = f2b(fmaxf(a0.w*f0.w + c0.w, 0.f));
  u[4] = f2b(fmaxf(a1.x*f1.x + c1.x, 0.f));
  u[5] = f2b(fmaxf(a1.y*f1.y + c1.y, 0.f));
  u[6] = f2b(fmaxf(a1.z*f1.z + c1.z, 0.f));
  u[7] = f2b(fmaxf(a1.w*f1.w + c1.w, 0.f));
  *(uint4*)(out + base) = v;
}

// ---------------------------------------------------------------- gathered column stats (strided):
// v[r,c] = Z[fs[r]*S + c] + C[(r>>3)*S + c];  acc[c] += sum, acc[O+c] += sumsq  (fp32)
__global__ __launch_bounds__(256) void gstats(const float* __restrict__ Z,
                                              const float* __restrict__ C,
                                              const int* __restrict__ fs,
                                              int S, int O,        // row stride, col count (512 or 1024)
                                              float* __restrict__ acc) {
  const int t = threadIdx.x;
  const int cq = O >> 2;                 // float4 cols
  const int c = (t & (cq - 1)) << 2;
  const int rof = t / cq;
  const int rstep = 256 / cq;            // 2 (O=512) or 1 (O=1024)
  const long rbase = (long)blockIdx.x * 128;   // 128 rows per block
  float s0=0,s1=0,s2=0,s3=0, q0=0,q1=0,q2=0,q3=0;
  for (int r = rof; r < 128; r += rstep) {
    const long rr = rbase + r;
    const long zr = (long)fs[rr] * S;
    const long cr = (rr >> 3) * (long)S;
    float4 z = *(const float4*)(Z + zr + c);
    float4 y = *(const float4*)(C + cr + c);
    float v0=z.x+y.x, v1=z.y+y.y, v2=z.z+y.z, v3=z.w+y.w;
    s0+=v0; s1+=v1; s2+=v2; s3+=v3;
    q0+=v0*v0; q1+=v1*v1; q2+=v2*v2; q3+=v3*v3;
  }
  atomicAdd(&acc[c+0], s0); atomicAdd(&acc[c+1], s1);
  atomicAdd(&acc[c+2], s2); atomicAdd(&acc[c+3], s3);
  atomicAdd(&acc[O+c+0], q0); atomicAdd(&acc[O+c+1], q1);
  atomicAdd(&acc[O+c+2], q2); atomicAdd(&acc[O+c+3], q3);
}

// ---------------------------------------------------------------- gathered BN+ReLU+cast (strided):
// out[r,c] = f2b(relu(a[c]*(Z[fs[r]*S+c] + C[(r>>3)*S+c]) + cc[c]))   (single rounding)
__global__ __launch_bounds__(256) void gbn(const float* __restrict__ Z,
                                           const float* __restrict__ C,
                                           const int* __restrict__ fs,
                                           const float* __restrict__ a,
                                           const float* __restrict__ cc,
                                           int S,                   // fp32 row stride of Z/C
                                           int cprShift,            // log2(O/8): 6 for O=512, 7 for O=1024
                                           unsigned short* __restrict__ out) {
  const int O = 8 << cprShift;
  long gid = (long)blockIdx.x * 256 + threadIdx.x;
  long r = gid >> cprShift;
  int c = (int)(gid & ((1 << cprShift) - 1)) << 3;
  const long zr = (long)fs[r] * S;
  const long cr = (r >> 3) * (long)S;
  float4 z0 = *(const float4*)(Z + zr + c), z1 = *(const float4*)(Z + zr + c + 4);
  float4 y0 = *(const float4*)(C + cr + c), y1 = *(const float4*)(C + cr + c + 4);
  float4 a0 = *(const float4*)(a + c),      a1 = *(const float4*)(a + c + 4);
  float4 b0 = *(const float4*)(cc + c),     b1 = *(const float4*)(cc + c + 4);
  uint4 v; unsigned short* u = (unsigned short*)&v;
  u[0] = f2b(fmaxf(a0.x*(z0.x+y0.x) + b0.x, 0.f));
  u[1] = f2b(fmaxf(a0.y*(z0.y+y0.y) + b0.y, 0.f));
  u[2] = f2b(fmaxf(a0.z*(z0.z+y0.z) + b0.z, 0.f));
  u[3] = f2b(fmaxf(a0.w*(z0.w+y0.w) + b0.w, 0.f));
  u[4] = f2b(fmaxf(a1.x*(z1.x+y1.x) + b1.x, 0.f));
  u[5] = f2b(fmaxf(a1.y*(z1.y+y1.y) + b1.y, 0.f));
  u[6] = f2b(fmaxf(a1.z*(z1.z+y1.z) + b1.z, 0.f));
  u[7] = f2b(fmaxf(a1.w*(z1.w+y1.w) + b1.w, 0.f));
  *(uint4*)(out + r*O + c) = v;
}

// ---------------------------------------------------------------- KNN top-8
__global__ __launch_bounds__(256) void knn_kernel(const float* __restrict__ xyz,
                                                  int* __restrict__ flat_src) {
  __shared__ float px[1024], py[1024], pz[1024], sq[1024];
  int b = blockIdx.x;
  for (int i = threadIdx.x; i < 1024; i += 256) {
    float x = xyz[(b*1024 + i)*3 + 0];
    float y = xyz[(b*1024 + i)*3 + 1];
    float z = xyz[(b*1024 + i)*3 + 2];
    px[i] = x; py[i] = y; pz[i] = z; sq[i] = x*x + y*y + z*z;
  }
  __syncthreads();
  int q = blockIdx.y * 256 + threadIdx.x;
  float qx = px[q], qy = py[q], qz = pz[q], qs = sq[q];
  float bd[8]; int bi[8];
  #pragma unroll
  for (int j = 0; j < 8; ++j) { bd[j] = 3.4e38f; bi[j] = 0; }
  for (int m = 0; m < 1024; ++m) {
    float dot = qx*px[m] + qy*py[m] + qz*pz[m];
    float d2 = qs + sq[m] - 2.f*dot;      // exact reference formula (tie behavior)
    if (d2 < bd[7]) {
      bd[7] = d2; bi[7] = m;
      #pragma unroll
      for (int j = 7; j > 0; --j) {
        if (bd[j] < bd[j-1]) {
          float td = bd[j]; bd[j] = bd[j-1]; bd[j-1] = td;
          int ti = bi[j]; bi[j] = bi[j-1]; bi[j-1] = ti;
        }
      }
    }
  }
  #pragma unroll
  for (int j = 0; j < 8; ++j) flat_src[(b*1024 + q)*8 + j] = b*1024 + bi[j];
}

// ---------------------------------------------------------------- weight diff: fp32 -> bf16 (hi - lo half)
__global__ __launch_bounds__(256) void wdiff(const float* __restrict__ W, int H,
                                             unsigned short* __restrict__ WD) {
  int gid = blockIdx.x * 256 + threadIdx.x;
  int o = gid / H, h = gid - o*H;
  WD[gid] = f2b(W[o*2*H + H + h] - W[o*2*H + h]);
}

// ---------------------------------------------------------------- weight lo-half extract: fp32 -> bf16
__global__ __launch_bounds__(256) void cvt_lo(const float* __restrict__ W, int H,
                                              unsigned short* __restrict__ out) {
  int gid = blockIdx.x * 256 + threadIdx.x;
  int o = gid / H, h = gid - o*H;
  out[gid] = f2b(W[o*2*H + h]);
}

// ---------------------------------------------------------------- MFMA GEMM (128x128 tile, BK=64, XOR-swizzled LDS)
// Round-9 kernel verbatim (best measured config: B2 316 us, FETCH 90 MB).
// XCD-chunked block remap (T1): swz = (id&7)*(nwg/8) + id>>3 over col-fast ordering.
// Staging: global_load_lds w=16, source chunk (l&7)^(l>>3); read chunk (kk*4+quad)^(lr&7).
// Maxmin epilogue: register/shuffle (no LDS, no barriers).
union GemmSmem {
  struct { unsigned short A[128*64]; unsigned short W[128*64]; } st;   // 32 KB
  struct { float redS[128*8]; float redS2[128*8]; } fst;               // 8 KB (fused stats)
};

__global__ __launch_bounds__(256) void gemm_kernel(
    const unsigned short* __restrict__ A16,   // bf16 A
    long strideA,
    const int* __restrict__ rowmap,
    const unsigned short* __restrict__ W, int strideW,
    int K, int O,                             // K multiple of 64
    const float* __restrict__ addC,           // fp32 [rows/8][O] added pre-store/stats
    unsigned short* __restrict__ outB,        // plain path: bf16 out (stats still fp32)
    float* __restrict__ outF,                 // plain path: fp32 out
    float* __restrict__ statsP,               // plain path: fused col stats, or NULL
    float* __restrict__ ymax, float* __restrict__ ymin,  // maxmin path
    float* __restrict__ statsMM)
{
  __shared__ GemmSmem sm;

  const int t = threadIdx.x;
  const int wave = t >> 6, lane = t & 63, quad = lane >> 4, lr = lane & 15;
  const int wr0 = (wave >> 1) * 64, wc0 = (wave & 1) * 64;

  // XCD-chunked block remap (grid = dim3(NCB, NRB), nwg % 8 == 0)
  const int nwgx = gridDim.x;
  const int nwg = nwgx * gridDim.y;
  const int id = blockIdx.y * nwgx + blockIdx.x;
  const int swz = (id & 7) * (nwg >> 3) + (id >> 3);
  const int rowB = swz / nwgx;
  const int colB = swz - rowB * nwgx;
  const long rowBase = (long)rowB * 128;
  const int colBase = colB * 128;

  // staging geometry: wave w, issue j covers LDS rows [w*32+j*8, +8); lane l -> row +(l>>3),
  // phys chunk l&7; source logical chunk = (l&7)^(l>>3)  (the XOR involution, row&7 = l>>3)
  const int lrow = lane >> 3;                       // 0..7
  const int lchk = ((lane & 7) ^ lrow) << 3;        // source chunk offset in shorts
  const unsigned short* pa[4];
  const unsigned short* pw[4];
  #pragma unroll
  for (int j = 0; j < 4; ++j) {
    int r = wave*32 + j*8 + lrow;
    long sA = rowmap ? (long)rowmap[rowBase + r] : rowBase + r;
    pa[j] = A16 + sA * strideA + lchk;
    pw[j] = W + (long)(colBase + r) * strideW + lchk;
  }

  f32x4 acc[4][4];
  #pragma unroll
  for (int i = 0; i < 4; ++i)
    #pragma unroll
    for (int j = 0; j < 4; ++j)
      acc[i][j] = (f32x4){0.f, 0.f, 0.f, 0.f};

  for (int k0 = 0; k0 < K; k0 += 64) {
    __syncthreads();                 // previous iter's LDS reads done
    #pragma unroll
    for (int j = 0; j < 4; ++j) {
      gload16(pa[j] + k0, &sm.st.A[wave*2048 + j*512]);
      gload16(pw[j] + k0, &sm.st.W[wave*2048 + j*512]);
    }
    __syncthreads();                 // drains vmcnt(0): DMA data visible

    #pragma unroll
    for (int kk = 0; kk < 2; ++kk) {
      const int coff = (((kk*4 + quad) ^ (lr & 7)) << 3);   // swizzled chunk, constant/lane
      bf8_t af[4], bfr[4];
      #pragma unroll
      for (int s = 0; s < 4; ++s) {
        af[s]  = *(const bf8_t*)&sm.st.A[(wr0 + s*16 + lr)*64 + coff];
        bfr[s] = *(const bf8_t*)&sm.st.W[(wc0 + s*16 + lr)*64 + coff];
      }
      #pragma unroll
      for (int sr = 0; sr < 4; ++sr)
        #pragma unroll
        for (int sc = 0; sc < 4; ++sc)
          acc[sr][sc] = __builtin_amdgcn_mfma_f32_16x16x32_bf16(af[sr], bfr[sc], acc[sr][sc], 0, 0, 0);
    }
  }

  if (!ymax) {
    // plain epilogue: center-add, bf16/fp32 store, optional fused per-channel stats (fp32 pre-round)
    float s[4] = {0.f,0.f,0.f,0.f}, s2[4] = {0.f,0.f,0.f,0.f};
    #pragma unroll
    for (int sc = 0; sc < 4; ++sc) {
      int col = colBase + wc0 + sc*16 + lr;
      #pragma unroll
      for (int sr = 0; sr < 4; ++sr) {
        #pragma unroll
        for (int r = 0; r < 4; ++r) {
          long row = rowBase + wr0 + sr*16 + quad*4 + r;
          float v = acc[sr][sc][r];
          if (addC) v += addC[(row >> 3) * (long)O + col];
          if (outF) outF[row * (long)O + col] = v;
          else      outB[row * (long)O + col] = f2b(v);
          s[sc] += v; s2[sc] += v*v;
        }
      }
    }
    if (statsP) {
      __syncthreads();   // all waves done reading sm.st before aliasing as fst
      int q8 = quad + 4*(wave >> 1);
      #pragma unroll
      for (int sc = 0; sc < 4; ++sc) {
        int colL = wc0 + sc*16 + lr;
        sm.fst.redS[colL*8 + q8]  = s[sc];
        sm.fst.redS2[colL*8 + q8] = s2[sc];
      }
      __syncthreads();
      if (t < 128) {
        float S = 0.f, S2 = 0.f;
        #pragma unroll
        for (int j = 0; j < 8; ++j) { S += sm.fst.redS[t*8 + j]; S2 += sm.fst.redS2[t*8 + j]; }
        atomicAdd(&statsP[colBase + t], S);
        atomicAdd(&statsP[O + colBase + t], S2);
      }
    }
  } else {
    // maxmin epilogue: register/shuffle, no LDS, no barriers.
    #pragma unroll
    for (int sc = 0; sc < 4; ++sc) {
      int col = colBase + wc0 + sc*16 + lr;
      float s = 0.f, s2v = 0.f;
      #pragma unroll
      for (int sr = 0; sr < 4; ++sr) {
        float mx = acc[sr][sc][0], mn = acc[sr][sc][0];
        s += acc[sr][sc][0]; s2v += acc[sr][sc][0]*acc[sr][sc][0];
        #pragma unroll
        for (int r = 1; r < 4; ++r) {
          float v = acc[sr][sc][r];
          mx = fmaxf(mx, v); mn = fminf(mn, v);
          s += v; s2v += v*v;
        }
        mx = fmaxf(mx, __shfl_xor(mx, 16));
        mn = fminf(mn, __shfl_xor(mn, 16));
        if ((quad & 1) == 0) {
          long orow = (long)rowB*16 + (wave >> 1)*8 + sr*2 + (quad >> 1);
          ymax[orow * O + col] = mx;
          ymin[orow * O + col] = mn;
        }
      }
      s   += __shfl_xor(s, 16);   s   += __shfl_xor(s, 32);
      s2v += __shfl_xor(s2v, 16); s2v += __shfl_xor(s2v, 32);
      if (quad == 0) {
        atomicAdd(&statsMM[col], s);
        atomicAdd(&statsMM[O + col], s2v);
      }
    }
  }
}

// ---------------------------------------------------------------- l0 from A2 maxmin
__global__ __launch_bounds__(256) void to_l0(const float* __restrict__ ymax,
                                             const float* __restrict__ ymin,
                                             const float* __restrict__ a, const float* __restrict__ cc,
                                             unsigned short* __restrict__ l0) {
  int gid = blockIdx.x * 256 + threadIdx.x;   // 8192*512
  int c = gid & 511;
  float A = a[c];
  float v = (A >= 0.f) ? ymax[gid] : ymin[gid];
  l0[gid] = f2b(fmaxf(A*v + cc[c], 0.f));
}

// ---------------------------------------------------------------- final BN+ReLU + transpose, fp32
__global__ __launch_bounds__(256) void final_out(const float* __restrict__ ymax,
                                                 const float* __restrict__ ymin,
                                                 const float* __restrict__ a, const float* __restrict__ cc,
                                                 float* __restrict__ out) {
  __shared__ float tile[32][33];
  int b = blockIdx.x, ct = blockIdx.y * 32, nt = blockIdx.z * 32;
  int tc = threadIdx.x & 31, tr = threadIdx.x >> 5;
  #pragma unroll
  for (int i = 0; i < 4; ++i) {
    int n = nt + tr + i*8;
    int c = ct + tc;
    float A = a[c];
    long idx = ((long)(b*1024 + n))*1024 + c;
    float v = (A >= 0.f) ? ymax[idx] : ymin[idx];
    tile[tr + i*8][tc] = fmaxf(A*v + cc[c], 0.f);
  }
  __syncthreads();
  #pragma unroll
  for (int i = 0; i < 4; ++i) {
    int c = ct + tr + i*8;
    int n = nt + tc;
    out[((long)(b*1024 + c))*1024 + n] = tile[tc][tr + i*8];
  }
}

// ================================================================ host
extern "C" void kernel_launch(void* const* d_in, const int* in_sizes, int n_in,
                              void* d_out, int out_size, void* d_ws, size_t ws_size,
                              hipStream_t stream) {
  const float* xyz = (const float*)d_in[0];
  const float* W1  = (const float*)d_in[1];
  const float* g1  = (const float*)d_in[2];
  const float* b1  = (const float*)d_in[3];
  const float* W2  = (const float*)d_in[4];
  const float* g2  = (const float*)d_in[5];
  const float* b2  = (const float*)d_in[6];
  const float* WA1 = (const float*)d_in[7];
  const float* gA1 = (const float*)d_in[8];
  const float* bA1 = (const float*)d_in[9];
  const float* WA2 = (const float*)d_in[10];
  const float* gA2 = (const float*)d_in[11];
  const float* bA2 = (const float*)d_in[12];
  const float* WB1 = (const float*)d_in[13];
  const float* gB1 = (const float*)d_in[14];
  const float* bB1 = (const float*)d_in[15];
  const float* WB2 = (const float*)d_in[16];
  const float* gB2 = (const float*)d_in[17];
  const float* bB2 = (const float*)d_in[18];
  float* out = (float*)d_out;

  char* w = (char*)d_ws;
  const size_t MB = 1048576;

  // -------- small zone [0, 8 MB) --------
  size_t off = 0;
  auto nxt = [&](size_t bytes) { void* p = w + off; off = (off + bytes + 255) & ~(size_t)255; return p; };
  int*            flat_src = (int*)nxt(262144);
  unsigned short* W2b   = (unsigned short*)nxt(32768);
  unsigned short* WcatA = (unsigned short*)nxt(524288);   // [WDA(512x256) ; WA1lo(512x256)]
  unsigned short* WA2b  = (unsigned short*)nxt(524288);
  unsigned short* WcatB = (unsigned short*)nxt(2097152);  // [WDB(1024x512) ; WB1lo(1024x512)]
  unsigned short* WB2b  = (unsigned short*)nxt(2097152);
  float* statsZone = (float*)nxt(27136);
  float* affZone   = (float*)nxt(27136);

  // -------- big zone (lifetime-aliased, peak 200 MB) --------
  float*          y1f   = (float*)(w + 193*MB);           // [193,195)
  unsigned short* x2in  = (unsigned short*)(w + 195*MB);  // [195,196)
  float*          y2f   = (float*)(w + 196*MB);           // [196,204)
  unsigned short* xA1   = (unsigned short*)(w + 204*MB);  // [204,208)
  float*          YA    = (float*)(w + 8*MB);             // [8,40)    merged A1 out: cols 0-511 center, 512-1023 z
  unsigned short* xA2   = (unsigned short*)(w + 40*MB);   // [40,104)  gathered+BN'd (64 MB)
  float*          ymaxA = (float*)(w + 104*MB);           // [104,120)
  float*          yminA = (float*)(w + 120*MB);           // [120,136)
  unsigned short* l0    = (unsigned short*)(w + 136*MB);  // [136,144)
  float*          YB    = (float*)(w + 8*MB);             // [8,72)    merged B1 out: cols 0-1023 center, 1024-2047 z (YA/xA2 dead)
  unsigned short* yB1b  = (unsigned short*)(w + 72*MB);   // [72,200)  gathered+BN'd (128 MB; l0 dead by then)
  float*          ymaxB = (float*)(w + 8*MB);             // [8,40)    YB dead after gbn B
  float*          yminB = (float*)(w + 40*MB);            // [40,72)

  float* acc1  = statsZone;          // 2*64
  float* acc2  = statsZone + 128;    // 2*256
  float* accA1 = statsZone + 640;    // 2*512
  float* accA2 = statsZone + 1664;   // 2*512
  float* accB1 = statsZone + 2688;   // 2*1024
  float* accB2 = statsZone + 4736;   // 2*1024

  float* a1  = affZone;        float* cc1  = affZone + 64;
  float* a2  = affZone + 128;  float* cc2  = affZone + 384;
  float* aA1 = affZone + 640;  float* ccA1 = affZone + 1152;
  float* aA2 = affZone + 1664; float* ccA2 = affZone + 2176;
  float* aB1 = affZone + 2688; float* ccB1 = affZone + 3712;
  float* aB2 = affZone + 4736; float* ccB2 = affZone + 5760;

  hipMemsetAsync(statsZone, 0, 6784 * 4, stream);

  // weight conversions: diffs into Wcat first half, lo-halves into Wcat second half
  cvt_f2b<<<64, 256, 0, stream>>>(W2, W2b, 16384);
  wdiff<<<512, 256, 0, stream>>>(WA1, 256, WcatA);
  cvt_lo<<<512, 256, 0, stream>>>(WA1, 256, WcatA + 131072);
  cvt_f2b<<<1024, 256, 0, stream>>>(WA2, WA2b, 262144);
  wdiff<<<2048, 256, 0, stream>>>(WB1, 512, WcatB);
  cvt_lo<<<2048, 256, 0, stream>>>(WB1, 512, WcatB + 524288);
  cvt_f2b<<<4096, 256, 0, stream>>>(WB2, WB2b, 1048576);

  // stage 1 + BN
  stage1<<<2048, 256, 0, stream>>>(xyz, W1, y1f);
  colstats<<<dim3(1, 8), 256, 0, stream>>>(y1f, 64, acc1);
  finalize_stats<<<1, 256, 0, stream>>>(acc1, g1, b1, 64, 1.f/8192.f, a1, cc1);
  bnrelu_cast<<<256, 256, 0, stream>>>(y1f, a1, cc1, 63, x2in);

  // stage 2 (bf16 A, fp32 out, fused stats)   grid = (colBlocks, rowBlocks)
  gemm_kernel<<<dim3(2, 64), 256, 0, stream>>>(x2in, 64, nullptr,
                                               W2b, 64, 64, 256,
                                               nullptr, nullptr, y2f, acc2, nullptr, nullptr, nullptr);
  finalize_stats<<<1, 256, 0, stream>>>(acc2, g2, b2, 256, 1.f/8192.f, a2, cc2);
  bnrelu_cast<<<1024, 256, 0, stream>>>(y2f, a2, cc2, 255, xA1);

  // knn
  knn_kernel<<<dim3(8, 4), 256, 0, stream>>>(xyz, flat_src);

  // stage A1 MERGED: one GEMM over [WDA ; WA1lo] -> YA [8192][1024]
  // (center = cols 0-511, z = cols 512-1023; gather commutes with matmul)
  gemm_kernel<<<dim3(8, 64), 256, 0, stream>>>(xA1, 256, nullptr,
                                               WcatA, 256, 256, 1024,
                                               nullptr, nullptr, YA, nullptr, nullptr, nullptr, nullptr);
  gstats<<<512, 256, 0, stream>>>(YA + 512, YA, flat_src, 1024, 512, accA1);
  finalize_stats<<<2, 256, 0, stream>>>(accA1, gA1, bA1, 512, 1.f/65536.f, aA1, ccA1);
  gbn<<<16384, 256, 0, stream>>>(YA + 512, YA, flat_src, aA1, ccA1, 1024, 6, xA2);

  // stage A2: maxmin GEMM, plain bf16 A
  gemm_kernel<<<dim3(4, 512), 256, 0, stream>>>(xA2, 512, nullptr,
                                                WA2b, 512, 512, 512,
                                                nullptr, nullptr, nullptr, nullptr, ymaxA, yminA, accA2);
  finalize_stats<<<2, 256, 0, stream>>>(accA2, gA2, bA2, 512, 1.f/65536.f, aA2, ccA2);
  to_l0<<<16384, 256, 0, stream>>>(ymaxA, yminA, aA2, ccA2, l0);

  // stage B1 MERGED: one GEMM over [WDB ; WB1lo] -> YB [8192][2048]
  gemm_kernel<<<dim3(16, 64), 256, 0, stream>>>(l0, 512, nullptr,
                                                WcatB, 512, 512, 2048,
                                                nullptr, nullptr, YB, nullptr, nullptr, nullptr, nullptr);
  gstats<<<512, 256, 0, stream>>>(YB + 1024, YB, flat_src, 2048, 1024, accB1);
  finalize_stats<<<4, 256, 0, stream>>>(accB1, gB1, bB1, 1024, 1.f/65536.f, aB1, ccB1);
  gbn<<<32768, 256, 0, stream>>>(YB + 1024, YB, flat_src, aB1, ccB1, 2048, 7, yB1b);

  // stage B2: maxmin GEMM, plain bf16 A
  gemm_kernel<<<dim3(8, 512), 256, 0, stream>>>(yB1b, 1024, nullptr,
                                                WB2b, 1024, 1024, 1024,
                                                nullptr, nullptr, nullptr, nullptr, ymaxB, yminB, accB2);
  finalize_stats<<<4, 256, 0, stream>>>(accB2, gB2, bB2, 1024, 1.f/65536.f, aB2, ccB2);

  // final
  final_out<<<dim3(8, 32, 32), 256, 0, stream>>>(ymaxB, yminB, aB2, ccB2, out);
}